// Round 9
// baseline (474.901 us; speedup 1.0000x reference)
//
#include <hip/hip_runtime.h>
#include <math.h>

#define EPSF 1e-8f
#define MARGIN 4e-3f

constexpr int Bn = 16, Cc = 256, HW = 1024, Ee = 512, Vv = 8192;
constexpr int Mm = Bn * HW; // 16384 pixels

// d_out float offsets: z | z_q | decoder_input | tokens(float)
constexpr long O_Z   = 0;
constexpr long O_ZQ  = 8388608;
constexpr long O_DEC = 16777216;
constexpr long O_TOK = 25165824;

typedef __attribute__((ext_vector_type(8))) short s16x8;
typedef __attribute__((ext_vector_type(4))) short s16x4;
typedef __attribute__((ext_vector_type(8))) _Float16 f16x8;
typedef __attribute__((ext_vector_type(4))) float f32x4;

__device__ __forceinline__ unsigned short f2h(float x) {
    _Float16 h = (_Float16)x;
    return __builtin_bit_cast(unsigned short, h);
}
__device__ __forceinline__ float h2f(unsigned short b) {
    return (float)__builtin_bit_cast(_Float16, b);
}

// ---------------- k_prep: wT transpose + embedding norms/fp16 B + cnt zero ----------------

__global__ void k_prep(const float* __restrict__ w, float* __restrict__ wT,
                       const float* __restrict__ emb, float* __restrict__ en_inv,
                       float* __restrict__ en_norm, unsigned short* __restrict__ Bhi,
                       int* __restrict__ cnt) {
    int b = blockIdx.x, t = threadIdx.x;
    // --- embedding norm + normalized fp16 row (one wave per row, 4 rows/block)
    int v = b * 4 + (t >> 6);
    int lane = t & 63;
    const float* row = emb + (long)v * Ee + lane * 8;
    float4 d0 = *(const float4*)row;
    float4 d1 = *(const float4*)(row + 4);
    float s = 0.f;
    s = fmaf(d0.x, d0.x, s); s = fmaf(d0.y, d0.y, s);
    s = fmaf(d0.z, d0.z, s); s = fmaf(d0.w, d0.w, s);
    s = fmaf(d1.x, d1.x, s); s = fmaf(d1.y, d1.y, s);
    s = fmaf(d1.z, d1.z, s); s = fmaf(d1.w, d1.w, s);
#pragma unroll
    for (int off = 32; off; off >>= 1) s += __shfl_xor(s, off);
    float n = sqrtf(s);
    float inv = 1.0f / (EPSF + n);
    if (lane == 0) { en_norm[v] = EPSF + n; en_inv[v] = inv; }
    s16x8 h;
    h[0] = (short)f2h(d0.x * inv); h[1] = (short)f2h(d0.y * inv);
    h[2] = (short)f2h(d0.z * inv); h[3] = (short)f2h(d0.w * inv);
    h[4] = (short)f2h(d1.x * inv); h[5] = (short)f2h(d1.y * inv);
    h[6] = (short)f2h(d1.z * inv); h[7] = (short)f2h(d1.w * inv);
    *(s16x8*)(Bhi + (long)v * Ee + lane * 8) = h;
    // --- wT (blocks 0..511) and cnt zero (blocks 512..575)
    if (b < 512) {
        int gid = b * 256 + t;
        int c = gid >> 9, e = gid & 511;
        wT[gid] = w[e * Cc + c];
    } else if (b < 576) {
        cnt[(b - 512) * 256 + t] = 0;
    }
}

// ---------------- GEMM1 (+ fused per-pixel sumsq partials) ----------------

__global__ __launch_bounds__(256) void k_gemm1(const float* __restrict__ x,
                                               const float* __restrict__ wT,
                                               const float* __restrict__ bias,
                                               float* __restrict__ z,
                                               float* __restrict__ sumsq_part) {
    __shared__ float As[32][64];
    __shared__ float Bs[32][64];
    int m0 = blockIdx.x * 64;                 // pixel tile
    int b = m0 >> 10, hw0 = m0 & 1023;
    int e0 = blockIdx.y * 64;
    int t = threadIdx.x;
    int mi = t >> 4, ni = t & 15;
    float acc[4][4] = {};
    for (int c0 = 0; c0 < Cc; c0 += 32) {
#pragma unroll
        for (int q = 0; q < 2; ++q) {
            int f = t + 256 * q;
            int kk = f >> 4, m4 = (f & 15) * 4;
            *(float4*)&As[kk][m4] = *(const float4*)(x + ((long)(b * Cc + c0 + kk)) * HW + hw0 + m4);
            *(float4*)&Bs[kk][m4] = *(const float4*)(wT + (long)(c0 + kk) * Ee + e0 + m4);
        }
        __syncthreads();
#pragma unroll
        for (int kk = 0; kk < 32; ++kk) {
            float4 a = *(float4*)&As[kk][mi * 4];
            float4 bv = *(float4*)&Bs[kk][ni * 4];
            float av[4] = {a.x, a.y, a.z, a.w};
            float bb[4] = {bv.x, bv.y, bv.z, bv.w};
#pragma unroll
            for (int r = 0; r < 4; ++r)
#pragma unroll
                for (int c = 0; c < 4; ++c) acc[r][c] = fmaf(av[r], bb[c], acc[r][c]);
        }
        __syncthreads();
    }
    float sq[4] = {0.f, 0.f, 0.f, 0.f};
#pragma unroll
    for (int c = 0; c < 4; ++c) {
        int e = e0 + ni * 4 + c;
        float be = bias[e];
        float4 o = make_float4(acc[0][c] + be, acc[1][c] + be, acc[2][c] + be, acc[3][c] + be);
        *(float4*)(z + ((long)(b * Ee + e)) * HW + hw0 + mi * 4) = o;
        sq[0] = fmaf(o.x, o.x, sq[0]); sq[1] = fmaf(o.y, o.y, sq[1]);
        sq[2] = fmaf(o.z, o.z, sq[2]); sq[3] = fmaf(o.w, o.w, sq[3]);
    }
#pragma unroll
    for (int r = 0; r < 4; ++r)
#pragma unroll
        for (int off = 1; off < 16; off <<= 1) sq[r] += __shfl_xor(sq[r], off);
    if (ni == 0) {
#pragma unroll
        for (int r = 0; r < 4; ++r)
            sumsq_part[(long)(m0 + mi * 4 + r) * 8 + blockIdx.y] = sq[r];
    }
}

// ---------------- A split: zn -> A_hi/A_lo fp16 (also finalizes inv_zn) ----------------

__global__ void k_Asplit(const float* __restrict__ z, const float* __restrict__ sumsq_part,
                         unsigned short* __restrict__ Ahi, unsigned short* __restrict__ Alo,
                         float* __restrict__ inv_zn) {
    __shared__ float tile[64][65];
    __shared__ float inv_s[64];
    int p0 = (blockIdx.x >> 3) * 64;   // 256 p-tiles
    int e0 = (blockIdx.x & 7) * 64;    // 8 e-tiles
    int b = p0 >> 10, hw0 = p0 & 1023;
    int t = threadIdx.x;
    if (t < 64) {
        const float* sp = sumsq_part + (long)(p0 + t) * 8;
        float s = ((sp[0] + sp[1]) + (sp[2] + sp[3])) + ((sp[4] + sp[5]) + (sp[6] + sp[7]));
        float inv = 1.0f / (EPSF + sqrtf(s));
        inv_s[t] = inv;
        if ((blockIdx.x & 7) == 0) inv_zn[p0 + t] = inv;
    }
#pragma unroll
    for (int q = 0; q < 4; ++q) {
        int f = t + 256 * q;
        int e_l = f >> 4, p4 = (f & 15) * 4;
        float4 d = *(const float4*)(z + ((long)(b * Ee + e0 + e_l)) * HW + hw0 + p4);
        tile[e_l][p4 + 0] = d.x; tile[e_l][p4 + 1] = d.y;
        tile[e_l][p4 + 2] = d.z; tile[e_l][p4 + 3] = d.w;
    }
    __syncthreads();
#pragma unroll
    for (int q = 0; q < 4; ++q) {
        int f = t + 256 * q;
        int p_l = f >> 4, e4 = (f & 15) * 4;
        float inv = inv_s[p_l];
        s16x4 h, lo;
#pragma unroll
        for (int j = 0; j < 4; ++j) {
            float xv = tile[e4 + j][p_l] * inv;
            unsigned short hh = f2h(xv);
            h[j]  = (short)hh;
            lo[j] = (short)f2h(xv - h2f(hh));
        }
        long off = (long)(p0 + p_l) * Ee + e0 + e4;
        *(s16x4*)(Ahi + off) = h;
        *(s16x4*)(Alo + off) = lo;
    }
}

// ---------------- B-stationary fp16 MFMA sims, 4x8 blocking, barrier-free K-loop ----------------
// 2048 blocks = 32 m-groups x 64 v-stripes, 512 thr = 8 waves (stacked in m).
// Wave = 64m x 128v: acc[4 msub][8 nt]. Per K-step(32): 8 LDS B-reads + 4
// global A-reads feed 32 MFMA (1:4) -> LDS pipe 41us < MFMA pipe 66us per CU.
// B-stripe 128v x 512k fp16 = 128KB LDS, layout [slot][v ^ (slot&7)]:
//   - staged once: coalesced global read -> swizzled ds_write (8 lanes/bank
//     group = min rounds, conflict-free), ONE barrier total.
//   - frag read: 2-way aliasing only (free). No XOR mystery from R8.
// A streamed global->reg (16 rows x 64B fully-sectored segments, L2-resident).
// MFMA chain = 16 sequential K=32 steps, same order as R5-R8 -> bitwise-
// identical sims -> identical tokens/absmax.

__global__ __launch_bounds__(512, 2) void k_sims(const unsigned short* __restrict__ Ahi,
                                                 const unsigned short* __restrict__ Bhi,
                                                 float* __restrict__ part_v,
                                                 int* __restrict__ part_i,
                                                 float2* __restrict__ extras,
                                                 int* __restrict__ cnt) {
    __shared__ short Bs[64 * 1024];   // [slot 0..63][row' 0..127][8 shorts] = 128 KB

    const int t = threadIdx.x;
    const int wg = blockIdx.x;
    const int newid = (wg & 7) * 256 + (wg >> 3);   // XCD-chunked (2048 % 8 == 0)
    const int by = newid & 63;        // v-stripe 0..63
    const int mg = newid >> 6;        // m-group 0..31 (same XCD -> few m-groups: A L2-hot)
    const long n0 = (long)by * 128;
    const int wid = t >> 6, l = t & 63;
    const int l15 = l & 15, lg = l >> 4;
    const long m0w = (long)mg * 512 + wid * 64;

    // ---- stage B stripe once: coalesced read, conflict-free swizzled write
    {
        const int sl = t & 63;        // 16B-slot (k/8)
        const int rb = t >> 6;        // row base 0..7
#pragma unroll
        for (int j = 0; j < 16; ++j) {
            int r = j * 8 + rb;       // v-row 0..127
            s16x8 d = *(const s16x8*)(Bhi + (n0 + r) * Ee + sl * 8);
            *(s16x8*)&Bs[sl * 1024 + ((r ^ (sl & 7)) * 8)] = d;
        }
    }
    __syncthreads();   // the ONLY block-wide sync

    f32x4 acc[4][8];
#pragma unroll
    for (int ms = 0; ms < 4; ++ms)
#pragma unroll
        for (int nt = 0; nt < 8; ++nt) acc[ms][nt] = (f32x4){0.f, 0.f, 0.f, 0.f};

    const unsigned short* abase = Ahi + (m0w + l15) * Ee + lg * 8;

    for (int kt = 0; kt < 16; ++kt) {
        s16x8 af[4];
#pragma unroll
        for (int ms = 0; ms < 4; ++ms)
            af[ms] = *(const s16x8*)(abase + (long)ms * 16 * Ee + kt * 32);
        s16x8 bf[8];
        const int s = kt * 4 + lg;
        const int sx = (s & 7);
#pragma unroll
        for (int nt = 0; nt < 8; ++nt) {
            int vrow = nt * 16 + l15;
            bf[nt] = *(const s16x8*)&Bs[s * 1024 + ((vrow ^ sx) * 8)];
        }
#pragma unroll
        for (int ms = 0; ms < 4; ++ms)
#pragma unroll
            for (int nt = 0; nt < 8; ++nt)
                acc[ms][nt] = __builtin_amdgcn_mfma_f32_16x16x32_f16(
                    __builtin_bit_cast(f16x8, af[ms]),
                    __builtin_bit_cast(f16x8, bf[nt]), acc[ms][nt], 0, 0, 0);
    }

    // ---- in-wave epilogue (C/D: col = l15, row = lg*4 + rg) ----
#pragma unroll
    for (int ms = 0; ms < 4; ++ms)
#pragma unroll
        for (int rg = 0; rg < 4; ++rg) {
            float best = -3e38f; int bi = 0x7FFFFFFF;
#pragma unroll
            for (int nt = 0; nt < 8; ++nt) {
                float val = acc[ms][nt][rg];
                int idx = (int)n0 + nt * 16 + l15;
                if (val > best) { best = val; bi = idx; }
            }
#pragma unroll
            for (int off = 1; off < 16; off <<= 1) {   // reduce over the 16 l15 lanes
                float ov = __shfl_xor(best, off);
                int oi = __shfl_xor(bi, off);
                if (ov > best || (ov == best && oi < bi)) { best = ov; bi = oi; }
            }
            long p = m0w + ms * 16 + lg * 4 + rg;
            if (l15 == 0) {
                part_v[p * 64 + by] = best;
                part_i[p * 64 + by] = bi;
            }
            float thr = best - MARGIN;
#pragma unroll
            for (int nt = 0; nt < 8; ++nt) {
                float val = acc[ms][nt][rg];
                int idx = (int)n0 + nt * 16 + l15;
                if (val >= thr && idx != bi) {
                    int slot = atomicAdd(&cnt[p], 1);
                    if (slot < 64) extras[p * 64 + slot] = make_float2(val, __int_as_float(idx));
                }
            }
        }
}

// ---------------- k_pick: per-pixel global m1, candidate set, exact f32 rescore ----------------

__global__ __launch_bounds__(256) void k_pick(const float* __restrict__ part_v,
                                              const int* __restrict__ part_i,
                                              const float2* __restrict__ extras,
                                              const int* __restrict__ cnt,
                                              const unsigned short* __restrict__ Ahi,
                                              const unsigned short* __restrict__ Alo,
                                              const float* __restrict__ emb,
                                              const float* __restrict__ en_inv,
                                              int* __restrict__ tok_i,
                                              float* __restrict__ tok_f) {
    int p = blockIdx.x * 4 + (threadIdx.x >> 6);
    int lane = threadIdx.x & 63;
    float wv = part_v[(long)p * 64 + lane];
    int wi = part_i[(long)p * 64 + lane];
    // global fp16 max over the 64 stripe winners
    float m1 = wv;
#pragma unroll
    for (int off = 1; off < 64; off <<= 1) {
        float ov = __shfl_xor(m1, off);
        if (ov > m1) m1 = ov;
    }
    float thr = m1 - MARGIN;
    int n = cnt[p]; if (n > 64) n = 64;
    float ev = -3e38f; int ei = 0;
    if (lane < n) {
        float2 e2 = extras[(long)p * 64 + lane];
        ev = e2.x; ei = __float_as_int(e2.y);
    }
    unsigned long long mw = __ballot(wv >= thr);
    unsigned long long me = __ballot(ev >= thr);
    // preload this pixel's zn row slice (reconstructed f32)
    s16x8 ah = *(const s16x8*)(Ahi + (long)p * Ee + lane * 8);
    s16x8 al = *(const s16x8*)(Alo + (long)p * Ee + lane * 8);
    float a[8];
#pragma unroll
    for (int j = 0; j < 8; ++j)
        a[j] = h2f((unsigned short)ah[j]) + h2f((unsigned short)al[j]);

    float best = -3e38f; int bi = 0x7FFFFFFF;
    auto rescore = [&](int v) {
        const float* er = emb + (long)v * Ee + lane * 8;
        float4 b0 = *(const float4*)er;
        float4 b1 = *(const float4*)(er + 4);
        float s = 0.f;
        s = fmaf(a[0], b0.x, s); s = fmaf(a[1], b0.y, s);
        s = fmaf(a[2], b0.z, s); s = fmaf(a[3], b0.w, s);
        s = fmaf(a[4], b1.x, s); s = fmaf(a[5], b1.y, s);
        s = fmaf(a[6], b1.z, s); s = fmaf(a[7], b1.w, s);
#pragma unroll
        for (int off = 1; off < 64; off <<= 1) s += __shfl_xor(s, off);
        s *= en_inv[v];
        if (s > best || (s == best && v < bi)) { best = s; bi = v; }
    };
    while (mw) {
        int b = __ffsll(mw) - 1; mw &= mw - 1;
        rescore(__shfl(wi, b));
    }
    while (me) {
        int b = __ffsll(me) - 1; me &= me - 1;
        rescore(__shfl(ei, b));
    }
    if (lane == 0) { tok_i[p] = bi; tok_f[p] = (float)bi; }
}

// ---------------- finalize: z_q gather + straight-through blend ----------------

__global__ void k_final(const float* __restrict__ z, const float* __restrict__ emb,
                        const int* __restrict__ tok, const float* __restrict__ inv_zn,
                        const float* __restrict__ en_inv, const float* __restrict__ en_norm,
                        float* __restrict__ zq, float* __restrict__ dec) {
    long gid = (long)blockIdx.x * 256 + threadIdx.x;   // 0..8388607
    int hw = (int)(gid & 1023);
    int b  = (int)(gid >> 19);
    int p  = (b << 10) | hw;
    int e  = (int)((gid >> 10) & 511);
    int tk = tok[p];
    float zqv = emb[(long)tk * Ee + e];
    float nq  = en_norm[tk];
    float nzq = zqv * en_inv[tk];
    float zv  = z[gid];
    float nz  = zv * inv_zn[p];
    zq[gid]  = zqv;
    dec[gid] = (nz + (nzq - nz)) * nq;
}

// ---------------- launch ----------------

extern "C" void kernel_launch(void* const* d_in, const int* in_sizes, int n_in,
                              void* d_out, int out_size, void* d_ws, size_t ws_size,
                              hipStream_t stream) {
    const float* x     = (const float*)d_in[0];
    const float* w_pre = (const float*)d_in[1];
    const float* b_pre = (const float*)d_in[2];
    const float* emb   = (const float*)d_in[3];

    float* out  = (float*)d_out;
    float* z    = out + O_Z;
    float* zq   = out + O_ZQ;
    float* dec  = out + O_DEC;
    float* tokf = out + O_TOK;

    // zq region (32MB): Ahi | Alo  fp16 [16384][512] each (dead until k_final)
    unsigned short* Ahi = (unsigned short*)zq;
    unsigned short* Alo = Ahi + (long)Mm * Ee;
    // dec region (8M floats): Bhi(2M) | part_v(1M) | part_i(1M) | extras(2M) | cnt | sumsq
    unsigned short* Bhi = (unsigned short*)dec;
    float*  part_v = dec + 2 * 1024 * 1024;
    int*    part_i = (int*)(dec + 3 * 1024 * 1024);
    float2* extras = (float2*)(dec + 4 * 1024 * 1024);
    int*    cnt    = (int*)(dec + 6 * 1024 * 1024);
    float*  sumsq_part = dec + 6 * 1024 * 1024 + 32768;   // 16384*8 floats

    float* ws      = (float*)d_ws;
    float* wT      = ws;                // 131072
    float* en_inv  = wT + 131072;       // 8192
    float* en_norm = en_inv + 8192;     // 8192
    float* inv_zn  = en_norm + 8192;    // 16384
    int*   tok_i   = (int*)(inv_zn + 16384); // 16384

    k_prep<<<2048, 256, 0, stream>>>(w_pre, wT, emb, en_inv, en_norm, Bhi, cnt);
    dim3 g1(Mm / 64, Ee / 64);
    k_gemm1<<<g1, 256, 0, stream>>>(x, wT, b_pre, z, sumsq_part);
    k_Asplit<<<2048, 256, 0, stream>>>(z, sumsq_part, Ahi, Alo, inv_zn);
    k_sims<<<2048, 512, 0, stream>>>(Ahi, Bhi, part_v, part_i, extras, cnt);
    k_pick<<<Mm / 4, 256, 0, stream>>>(part_v, part_i, extras, cnt, Ahi, Alo, emb,
                                       en_inv, tok_i, tokf);
    k_final<<<(int)(8388608 / 256), 256, 0, stream>>>(z, emb, tok_i, inv_zn, en_inv, en_norm, zq, dec);
}